// Round 1
// baseline (815.246 us; speedup 1.0000x reference)
//
#include <hip/hip_runtime.h>
#include <hip/hip_bf16.h>
#include <stdint.h>

#define DIMN 1024
#define N1C 32768
#define N2C 512
#define KTOP 64
#define MCAND 128

typedef unsigned short ushort_t;

__device__ __forceinline__ double wave_reduce_sum_d(double v) {
    #pragma unroll
    for (int off = 32; off > 0; off >>= 1)
        v += __shfl_down(v, off, 64);
    return v;
}

__device__ __forceinline__ float bflo(unsigned u) { return __uint_as_float(u << 16); }
__device__ __forceinline__ float bfhi(unsigned u) { return __uint_as_float(u & 0xFFFF0000u); }

// ---------------------------------------------------------------------------
// Kernel 1: per-row LayerNorm stats (fp64) + L2-normalized output (bf16)
// block = 256 threads, one block per row. DIMN=1024 -> 4 elems/thread.
// stats[row*3 + {0,1,2}] = mu, rstd, invnorm  (all fp64)
// ---------------------------------------------------------------------------
__global__ __launch_bounds__(256) void ln_norm_stats(
    const float* __restrict__ x, const float* __restrict__ gamma,
    const float* __restrict__ beta, __hip_bfloat16* __restrict__ xn,
    double* __restrict__ stats) {
    const int row = blockIdx.x;
    const int tid = threadIdx.x;
    const int lane = tid & 63, wave = tid >> 6;
    const float* xr = x + (size_t)row * DIMN;

    __shared__ double red[8];
    __shared__ double bmu, brstd, binvn;

    float xv[4];
    double s = 0.0, s2 = 0.0;
    #pragma unroll
    for (int j = 0; j < 4; ++j) {
        xv[j] = xr[tid + 256 * j];
        double xd = (double)xv[j];
        s += xd; s2 += xd * xd;
    }
    s = wave_reduce_sum_d(s);
    s2 = wave_reduce_sum_d(s2);
    if (lane == 0) { red[wave] = s; red[4 + wave] = s2; }
    __syncthreads();
    if (tid == 0) {
        double S  = red[0] + red[1] + red[2] + red[3];
        double S2 = red[4] + red[5] + red[6] + red[7];
        double mu = S / (double)DIMN;
        double var = S2 / (double)DIMN - mu * mu;
        bmu = mu;
        brstd = 1.0 / sqrt(var + 1e-5);
    }
    __syncthreads();
    const double mu = bmu, rstd = brstd;

    double yv[4];
    double q = 0.0;
    #pragma unroll
    for (int j = 0; j < 4; ++j) {
        int d = tid + 256 * j;
        double y = ((double)xv[j] - mu) * rstd * (double)gamma[d] + (double)beta[d];
        yv[j] = y;
        q += y * y;
    }
    q = wave_reduce_sum_d(q);
    if (lane == 0) red[wave] = q;
    __syncthreads();
    if (tid == 0) {
        double Q = red[0] + red[1] + red[2] + red[3];
        double nrm = sqrt(Q);
        double invn = 1.0 / fmax(nrm, 1e-8);
        binvn = invn;
        stats[(size_t)row * 3 + 0] = mu;
        stats[(size_t)row * 3 + 1] = rstd;
        stats[(size_t)row * 3 + 2] = invn;
    }
    __syncthreads();
    const double invn = binvn;
    #pragma unroll
    for (int j = 0; j < 4; ++j) {
        int d = tid + 256 * j;
        xn[(size_t)row * DIMN + d] = __float2bfloat16((float)(yv[j] * invn));
    }
}

// ---------------------------------------------------------------------------
// Kernel 2: candidate GEMM  sim[q][n] = sum_k x2n[q][k]*x1n[n][k]  (bf16 in,
// fp32 accum, bf16 out). Tile 64(q) x 64(n), BK=32, 256 threads, 4x4/thread.
// ---------------------------------------------------------------------------
#define TQ 64
#define TN 64
#define BKK 32

__global__ __launch_bounds__(256) void sim_gemm(
    const __hip_bfloat16* __restrict__ x2n, const __hip_bfloat16* __restrict__ x1n,
    __hip_bfloat16* __restrict__ sim) {
    __shared__ float As[BKK][TQ + 4];  // [k][q]  row stride 68 floats = 272B (16B aligned)
    __shared__ float Bs[BKK][TN + 4];  // [k][n]

    const int nb = blockIdx.x;   // 0..511
    const int qb = blockIdx.y;   // 0..7
    const int tid = threadIdx.x;
    const int tx = tid & 15, ty = tid >> 4;
    const int lrow = tid >> 2;          // 0..63
    const int lc8 = (tid & 3) * 8;      // 0,8,16,24

    const ushort_t* a_src = (const ushort_t*)x2n + (size_t)(qb * TQ + lrow) * DIMN + lc8;
    const ushort_t* b_src = (const ushort_t*)x1n + (size_t)(nb * TN + lrow) * DIMN + lc8;

    float acc[4][4];
    #pragma unroll
    for (int i = 0; i < 4; ++i)
        #pragma unroll
        for (int j = 0; j < 4; ++j) acc[i][j] = 0.0f;

    for (int kt = 0; kt < DIMN; kt += BKK) {
        uint4 av = *(const uint4*)(a_src + kt);
        uint4 bv = *(const uint4*)(b_src + kt);
        const unsigned* aw = (const unsigned*)&av;
        const unsigned* bw = (const unsigned*)&bv;
        #pragma unroll
        for (int w = 0; w < 4; ++w) {
            As[lc8 + 2 * w][lrow]     = bflo(aw[w]);
            As[lc8 + 2 * w + 1][lrow] = bfhi(aw[w]);
            Bs[lc8 + 2 * w][lrow]     = bflo(bw[w]);
            Bs[lc8 + 2 * w + 1][lrow] = bfhi(bw[w]);
        }
        __syncthreads();
        #pragma unroll
        for (int kk = 0; kk < BKK; ++kk) {
            float4 a4 = *(const float4*)&As[kk][ty * 4];
            float4 b4 = *(const float4*)&Bs[kk][tx * 4];
            float aa[4] = {a4.x, a4.y, a4.z, a4.w};
            float bb[4] = {b4.x, b4.y, b4.z, b4.w};
            #pragma unroll
            for (int i = 0; i < 4; ++i)
                #pragma unroll
                for (int j = 0; j < 4; ++j)
                    acc[i][j] = fmaf(aa[i], bb[j], acc[i][j]);
        }
        __syncthreads();
    }
    #pragma unroll
    for (int i = 0; i < 4; ++i) {
        int q = qb * TQ + ty * 4 + i;
        #pragma unroll
        for (int j = 0; j < 4; ++j) {
            int n = nb * TN + tx * 4 + j;
            sim[(size_t)q * N1C + n] = __float2bfloat16(acc[i][j]);
        }
    }
}

// ---------------------------------------------------------------------------
// Kernel 3: per-row top-MCAND candidate extraction from bf16 sim row.
// One block (256 thr) per q row; row keys in LDS; MCAND rounds of argmax.
// Keys are monotone-mapped bf16 bits; packed (key<<16)|(0xFFFF-idx) so a
// single unsigned max gives (max value, min index) tie-break.
// ---------------------------------------------------------------------------
__global__ __launch_bounds__(256) void topk_cand(
    const __hip_bfloat16* __restrict__ sim, int* __restrict__ cand) {
    const int q = blockIdx.x;
    const int tid = threadIdx.x;
    const int lane = tid & 63, wave = tid >> 6;

    __shared__ ushort_t key[N1C];       // 64 KB
    __shared__ unsigned redp[4];
    unsigned* keyPair = (unsigned*)key;

    const ushort_t* srow = (const ushort_t*)sim + (size_t)q * N1C;
    // load + monotone-map, 8 elems (one uint4) per thread per iter, 16 iters
    for (int it = 0; it < 16; ++it) {
        int e8 = (it * 256 + tid);      // group of 8 elements
        uint4 v = *(const uint4*)(srow + e8 * 8);
        const unsigned* vw = (const unsigned*)&v;
        #pragma unroll
        for (int w = 0; w < 4; ++w) {
            unsigned u = vw[w];
            unsigned u0 = u & 0xFFFFu, u1 = u >> 16;
            unsigned k0 = (u0 & 0x8000u) ? (0xFFFFu & ~u0) : (u0 | 0x8000u);
            unsigned k1 = (u1 & 0x8000u) ? (0xFFFFu & ~u1) : (u1 | 0x8000u);
            keyPair[e8 * 4 + w] = k0 | (k1 << 16);
        }
    }
    __syncthreads();

    for (int r = 0; r < MCAND; ++r) {
        unsigned best = 0;
        for (int s = 0; s < 64; ++s) {
            int dw = s * 256 + tid;                 // dword index, covers elems 2dw,2dw+1
            unsigned pk = keyPair[dw];
            unsigned e0 = (unsigned)(dw * 2);
            unsigned p0 = ((pk & 0xFFFFu) << 16) | (0xFFFFu - e0);
            unsigned p1 = (pk & 0xFFFF0000u)      | (0xFFFFu - (e0 + 1));
            unsigned m = p0 > p1 ? p0 : p1;
            best = best > m ? best : m;
        }
        #pragma unroll
        for (int off = 32; off > 0; off >>= 1) {
            unsigned o = __shfl_down(best, off, 64);
            best = best > o ? best : o;
        }
        if (lane == 0) redp[wave] = best;
        __syncthreads();
        if (tid == 0) {
            unsigned b01 = redp[0] > redp[1] ? redp[0] : redp[1];
            unsigned b23 = redp[2] > redp[3] ? redp[2] : redp[3];
            unsigned b = b01 > b23 ? b01 : b23;
            int widx = (int)(0xFFFFu - (b & 0xFFFFu));
            key[widx] = 0;                           // remove winner
            cand[(size_t)q * MCAND + r] = widx;
        }
        __syncthreads();
    }
}

// ---------------------------------------------------------------------------
// Kernel 4: fp64 rescore of MCAND candidates per row + exact top-64 output.
// One block (256 thr = 4 waves) per q row. Each wave scores one candidate at
// a time (64 lanes over DIMN). Final selection by wave 0.
// ---------------------------------------------------------------------------
__global__ __launch_bounds__(256) void rescore_topk(
    const float* __restrict__ x1, const float* __restrict__ x2,
    const float* __restrict__ g1, const float* __restrict__ b1,
    const float* __restrict__ g2, const float* __restrict__ b2,
    const double* __restrict__ stats1, const double* __restrict__ stats2,
    const int* __restrict__ cand, float* __restrict__ out) {
    const int q = blockIdx.x;
    const int tid = threadIdx.x;
    const int lane = tid & 63, wave = tid >> 6;

    __shared__ double y2s[DIMN];
    __shared__ double vals[MCAND];
    __shared__ int vidx[MCAND];

    const double mu2 = stats2[(size_t)q * 3 + 0];
    const double rstd2 = stats2[(size_t)q * 3 + 1];
    const double invn2 = stats2[(size_t)q * 3 + 2];
    #pragma unroll
    for (int j = 0; j < 4; ++j) {
        int d = tid + 256 * j;
        double y = ((double)x2[(size_t)q * DIMN + d] - mu2) * rstd2 * (double)g2[d] + (double)b2[d];
        y2s[d] = y * invn2;
    }
    __syncthreads();

    for (int c = wave; c < MCAND; c += 4) {
        int n = cand[(size_t)q * MCAND + c];
        double mu1 = stats1[(size_t)n * 3 + 0];
        double rstd1 = stats1[(size_t)n * 3 + 1];
        double invn1 = stats1[(size_t)n * 3 + 2];
        double acc = 0.0;
        #pragma unroll
        for (int j = 0; j < 16; ++j) {
            int d = lane + 64 * j;
            double y1 = (((double)x1[(size_t)n * DIMN + d] - mu1) * rstd1 * (double)g1[d]
                         + (double)b1[d]) * invn1;
            acc += y1 * y2s[d];
        }
        acc = wave_reduce_sum_d(acc);
        if (lane == 0) { vals[c] = acc; vidx[c] = n; }
    }
    __syncthreads();

    if (wave == 0) {
        double v0 = vals[lane],      v1 = vals[lane + 64];
        int    i0 = vidx[lane],      i1 = vidx[lane + 64];
        for (int k = 0; k < KTOP; ++k) {
            bool take0 = (v0 > v1) || (v0 == v1 && i0 < i1);
            double mv = take0 ? v0 : v1;
            int mi = take0 ? i0 : i1;
            int slot = take0 ? 0 : 1;
            int owner = lane;
            #pragma unroll
            for (int off = 32; off > 0; off >>= 1) {
                double ov = __shfl_down(mv, off, 64);
                int oi = __shfl_down(mi, off, 64);
                int oo = __shfl_down(owner, off, 64);
                int os = __shfl_down(slot, off, 64);
                bool take = (ov > mv) || (ov == mv && oi < mi);
                if (take) { mv = ov; mi = oi; owner = oo; slot = os; }
            }
            int wown = __shfl(owner, 0, 64);
            int wslot = __shfl(slot, 0, 64);
            int wmi = __shfl(mi, 0, 64);
            if (lane == 0) out[(size_t)q * KTOP + k] = (float)wmi * (1.0f / 32768.0f);
            if (lane == wown) {
                if (wslot == 0) v0 = -1e300; else v1 = -1e300;
            }
        }
    }
}

// ---------------------------------------------------------------------------
extern "C" void kernel_launch(void* const* d_in, const int* in_sizes, int n_in,
                              void* d_out, int out_size, void* d_ws, size_t ws_size,
                              hipStream_t stream) {
    const float* prior = (const float*)d_in[0];
    const float* clip  = (const float*)d_in[1];
    const float* g1    = (const float*)d_in[2];
    const float* b1    = (const float*)d_in[3];
    const float* g2    = (const float*)d_in[4];
    const float* b2    = (const float*)d_in[5];
    float* out = (float*)d_out;

    char* ws = (char*)d_ws;
    size_t off = 0;
    double* stats1 = (double*)(ws + off); off += (size_t)N1C * 3 * sizeof(double);   // 786432
    double* stats2 = (double*)(ws + off); off += (size_t)N2C * 3 * sizeof(double);   // 12288
    __hip_bfloat16* x1n = (__hip_bfloat16*)(ws + off); off += (size_t)N1C * DIMN * 2; // 64 MB
    __hip_bfloat16* x2n = (__hip_bfloat16*)(ws + off); off += (size_t)N2C * DIMN * 2; // 1 MB
    __hip_bfloat16* sim = (__hip_bfloat16*)(ws + off); off += (size_t)N2C * N1C * 2;  // 32 MB
    int* cand = (int*)(ws + off); off += (size_t)N2C * MCAND * sizeof(int);           // 256 KB

    ln_norm_stats<<<N1C, 256, 0, stream>>>(prior, g1, b1, x1n, stats1);
    ln_norm_stats<<<N2C, 256, 0, stream>>>(clip, g2, b2, x2n, stats2);

    dim3 gg(N1C / TN, N2C / TQ);
    sim_gemm<<<gg, 256, 0, stream>>>(x2n, x1n, sim);

    topk_cand<<<N2C, 256, 0, stream>>>(sim, cand);

    rescore_topk<<<N2C, 256, 0, stream>>>(prior, clip, g1, b1, g2, b2,
                                          stats1, stats2, cand, out);
}

// Round 2
// 248.991 us; speedup vs baseline: 3.2742x; 3.2742x over previous
//
#include <hip/hip_runtime.h>
#include <hip/hip_bf16.h>
#include <stdint.h>

#define DIMN 1024
#define N1C 32768
#define N2C 512
#define KTOP 64
#define MCAND 128
#define CAP 256

typedef unsigned short ushort_t;
typedef __attribute__((ext_vector_type(8))) short short8;
typedef __attribute__((ext_vector_type(4))) float f32x4;

__device__ __forceinline__ double wave_reduce_sum_d(double v) {
    #pragma unroll
    for (int off = 32; off > 0; off >>= 1)
        v += __shfl_down(v, off, 64);
    return v;
}

__device__ __forceinline__ void gload_lds16(const void* g, void* l) {
    __builtin_amdgcn_global_load_lds(
        (const __attribute__((address_space(1))) unsigned*)g,
        (__attribute__((address_space(3))) unsigned*)l, 16, 0, 0);
}

// ---------------------------------------------------------------------------
// Kernel 1: per-row LayerNorm stats (fp64) + L2-normalized output (bf16)
// ---------------------------------------------------------------------------
__global__ __launch_bounds__(256) void ln_norm_stats(
    const float* __restrict__ x, const float* __restrict__ gamma,
    const float* __restrict__ beta, __hip_bfloat16* __restrict__ xn,
    double* __restrict__ stats) {
    const int row = blockIdx.x;
    const int tid = threadIdx.x;
    const int lane = tid & 63, wave = tid >> 6;
    const float* xr = x + (size_t)row * DIMN;

    __shared__ double red[8];
    __shared__ double bmu, brstd, binvn;

    float xv[4];
    double s = 0.0, s2 = 0.0;
    #pragma unroll
    for (int j = 0; j < 4; ++j) {
        xv[j] = xr[tid + 256 * j];
        double xd = (double)xv[j];
        s += xd; s2 += xd * xd;
    }
    s = wave_reduce_sum_d(s);
    s2 = wave_reduce_sum_d(s2);
    if (lane == 0) { red[wave] = s; red[4 + wave] = s2; }
    __syncthreads();
    if (tid == 0) {
        double S  = red[0] + red[1] + red[2] + red[3];
        double S2 = red[4] + red[5] + red[6] + red[7];
        double mu = S / (double)DIMN;
        double var = S2 / (double)DIMN - mu * mu;
        bmu = mu;
        brstd = 1.0 / sqrt(var + 1e-5);
    }
    __syncthreads();
    const double mu = bmu, rstd = brstd;

    double yv[4];
    double q = 0.0;
    #pragma unroll
    for (int j = 0; j < 4; ++j) {
        int d = tid + 256 * j;
        double y = ((double)xv[j] - mu) * rstd * (double)gamma[d] + (double)beta[d];
        yv[j] = y;
        q += y * y;
    }
    q = wave_reduce_sum_d(q);
    if (lane == 0) red[wave] = q;
    __syncthreads();
    if (tid == 0) {
        double Q = red[0] + red[1] + red[2] + red[3];
        double nrm = sqrt(Q);
        double invn = 1.0 / fmax(nrm, 1e-8);
        binvn = invn;
        stats[(size_t)row * 3 + 0] = mu;
        stats[(size_t)row * 3 + 1] = rstd;
        stats[(size_t)row * 3 + 2] = invn;
    }
    __syncthreads();
    const double invn = binvn;
    #pragma unroll
    for (int j = 0; j < 4; ++j) {
        int d = tid + 256 * j;
        xn[(size_t)row * DIMN + d] = __float2bfloat16((float)(yv[j] * invn));
    }
}

// ---------------------------------------------------------------------------
// Kernel 2: candidate GEMM via MFMA. sim[q][n] = sum_k x2n[q][k]*x1n[n][k].
// 128x128 tile, BK=32, 256 thr = 4 waves (2x2), wave = 64x64 out = 4x4 frags
// of v_mfma_f32_16x16x32_bf16. Staging via global_load_lds width=16 into
// linear row-major LDS tiles (m97 structure, 2-barrier K-loop).
// ---------------------------------------------------------------------------
#define BM 128
#define BN 128
#define BKK 32

__global__ __launch_bounds__(256) void sim_gemm(
    const __hip_bfloat16* __restrict__ x2n, const __hip_bfloat16* __restrict__ x1n,
    __hip_bfloat16* __restrict__ sim) {
    __shared__ ushort_t As[BM][BKK];   // 8 KB, row stride 64 B (linear for gload_lds)
    __shared__ ushort_t Bs[BN][BKK];   // 8 KB

    const int n0 = blockIdx.x * BN;
    const int q0 = blockIdx.y * BM;
    const int tid = threadIdx.x;
    const int ln = tid & 63, wv = tid >> 6;
    const int wr = wv >> 1, wc = wv & 1;        // wave 2x2 grid, each 64x64 out

    const int st_r = ln >> 2;                   // staging: lane row-in-chunk
    const int st_c = (ln & 3) * 8;              // staging: lane k-offset (elems)

    const ushort_t* Ab = (const ushort_t*)x2n;
    const ushort_t* Bb = (const ushort_t*)x1n;

    f32x4 acc[4][4];
    #pragma unroll
    for (int m = 0; m < 4; ++m)
        #pragma unroll
        for (int n = 0; n < 4; ++n) acc[m][n] = (f32x4)0.0f;

    const int lr = ln & 15;
    const int lk = (ln >> 4) * 8;

    for (int kt = 0; kt < DIMN; kt += BKK) {
        // stage: 2 issues per operand; chunk ci = 16 rows = 1024 B, wave-uniform base
        #pragma unroll
        for (int i = 0; i < 2; ++i) {
            int ci = i * 4 + wv;
            int row = ci * 16 + st_r;
            gload_lds16(Ab + (size_t)(q0 + row) * DIMN + kt + st_c,
                        (char*)&As[0][0] + ci * 1024);
            gload_lds16(Bb + (size_t)(n0 + row) * DIMN + kt + st_c,
                        (char*)&Bs[0][0] + ci * 1024);
        }
        __syncthreads();

        short8 af[4], bfr[4];
        #pragma unroll
        for (int m = 0; m < 4; ++m)
            af[m] = *(const short8*)&As[wr * 64 + m * 16 + lr][lk];
        #pragma unroll
        for (int n = 0; n < 4; ++n)
            bfr[n] = *(const short8*)&Bs[wc * 64 + n * 16 + lr][lk];
        #pragma unroll
        for (int m = 0; m < 4; ++m)
            #pragma unroll
            for (int n = 0; n < 4; ++n)
                acc[m][n] = __builtin_amdgcn_mfma_f32_16x16x32_bf16(
                    af[m], bfr[n], acc[m][n], 0, 0, 0);
        __syncthreads();
    }

    // C/D layout: col = lane&15, row = (lane>>4)*4 + reg
    const int crow = (ln >> 4) * 4;
    #pragma unroll
    for (int m = 0; m < 4; ++m) {
        #pragma unroll
        for (int n = 0; n < 4; ++n) {
            int col = n0 + wc * 64 + n * 16 + lr;
            #pragma unroll
            for (int r = 0; r < 4; ++r) {
                int row = q0 + wr * 64 + m * 16 + crow + r;
                sim[(size_t)row * N1C + col] = __float2bfloat16(acc[m][n][r]);
            }
        }
    }
}

// ---------------------------------------------------------------------------
// Kernel 3: per-row candidate selection by threshold.
// Load row as monotone-mapped 16-bit keys into LDS; binary-search (16 passes)
// the largest threshold T with count(key >= T) >= MCAND; collect all >= T.
// ---------------------------------------------------------------------------
__global__ __launch_bounds__(256) void topk_cand(
    const __hip_bfloat16* __restrict__ sim, int* __restrict__ cand,
    int* __restrict__ cand_cnt) {
    const int q = blockIdx.x;
    const int tid = threadIdx.x;
    const int lane = tid & 63, wave = tid >> 6;

    __shared__ ushort_t key[N1C];       // 64 KB
    __shared__ unsigned wred[4];
    __shared__ unsigned bcast;
    __shared__ unsigned cnt;
    unsigned* keyPair = (unsigned*)key;

    const ushort_t* srow = (const ushort_t*)sim + (size_t)q * N1C;
    for (int it = 0; it < 16; ++it) {
        int e8 = it * 256 + tid;
        uint4 v = *(const uint4*)(srow + e8 * 8);
        const unsigned* vw = (const unsigned*)&v;
        uint4 kv;
        unsigned* kw = (unsigned*)&kv;
        #pragma unroll
        for (int w = 0; w < 4; ++w) {
            unsigned u = vw[w];
            unsigned u0 = u & 0xFFFFu, u1 = u >> 16;
            unsigned k0 = (u0 & 0x8000u) ? (0xFFFFu & ~u0) : (u0 | 0x8000u);
            unsigned k1 = (u1 & 0x8000u) ? (0xFFFFu & ~u1) : (u1 | 0x8000u);
            kw[w] = k0 | (k1 << 16);
        }
        *(uint4*)&keyPair[e8 * 4] = kv;
    }
    if (tid == 0) cnt = 0;
    __syncthreads();

    unsigned lo = 0, hi = 65536;
    for (int pass = 0; pass < 16; ++pass) {
        unsigned mid = (lo + hi) >> 1;
        unsigned c = 0;
        for (int s = 0; s < 64; ++s) {
            unsigned pk = keyPair[s * 256 + tid];   // stride-256: conflict-free
            c += ((pk & 0xFFFFu) >= mid) ? 1u : 0u;
            c += ((pk >> 16)     >= mid) ? 1u : 0u;
        }
        #pragma unroll
        for (int off = 32; off > 0; off >>= 1) c += __shfl_down(c, off, 64);
        if (lane == 0) wred[wave] = c;
        __syncthreads();
        if (tid == 0) bcast = wred[0] + wred[1] + wred[2] + wred[3];
        __syncthreads();
        if (bcast >= MCAND) lo = mid; else hi = mid;
    }
    const unsigned thr = lo;

    for (int s = 0; s < 64; ++s) {
        int dw = s * 256 + tid;
        unsigned pk = keyPair[dw];
        if ((pk & 0xFFFFu) >= thr) {
            unsigned p = atomicAdd(&cnt, 1u);
            if (p < CAP) cand[(size_t)q * CAP + p] = dw * 2;
        }
        if ((pk >> 16) >= thr) {
            unsigned p = atomicAdd(&cnt, 1u);
            if (p < CAP) cand[(size_t)q * CAP + p] = dw * 2 + 1;
        }
    }
    __syncthreads();
    if (tid == 0) cand_cnt[q] = (int)(cnt < CAP ? cnt : CAP);
}

// ---------------------------------------------------------------------------
// Kernel 4: fp64 rescore of candidates + exact top-64 (value desc, idx asc).
// ---------------------------------------------------------------------------
__global__ __launch_bounds__(256) void rescore_topk(
    const float* __restrict__ x1, const float* __restrict__ x2,
    const float* __restrict__ g1, const float* __restrict__ b1,
    const float* __restrict__ g2, const float* __restrict__ b2,
    const double* __restrict__ stats1, const double* __restrict__ stats2,
    const int* __restrict__ cand, const int* __restrict__ cand_cnt,
    float* __restrict__ out) {
    const int q = blockIdx.x;
    const int tid = threadIdx.x;
    const int lane = tid & 63, wave = tid >> 6;

    __shared__ double y2s[DIMN];
    __shared__ double vals[CAP];
    __shared__ int vidx[CAP];

    const int cnt = cand_cnt[q];
    vals[tid] = -1e300;
    vidx[tid] = 0x7FFFFFFF;

    const double mu2 = stats2[(size_t)q * 3 + 0];
    const double rstd2 = stats2[(size_t)q * 3 + 1];
    const double invn2 = stats2[(size_t)q * 3 + 2];
    #pragma unroll
    for (int j = 0; j < 4; ++j) {
        int d = tid + 256 * j;
        double y = ((double)x2[(size_t)q * DIMN + d] - mu2) * rstd2 * (double)g2[d] + (double)b2[d];
        y2s[d] = y * invn2;
    }
    __syncthreads();

    for (int c = wave; c < cnt; c += 4) {
        int n = cand[(size_t)q * CAP + c];
        double mu1 = stats1[(size_t)n * 3 + 0];
        double rstd1 = stats1[(size_t)n * 3 + 1];
        double invn1 = stats1[(size_t)n * 3 + 2];
        double acc = 0.0;
        #pragma unroll
        for (int j = 0; j < 16; ++j) {
            int d = lane + 64 * j;
            double y1 = (((double)x1[(size_t)n * DIMN + d] - mu1) * rstd1 * (double)g1[d]
                         + (double)b1[d]) * invn1;
            acc += y1 * y2s[d];
        }
        acc = wave_reduce_sum_d(acc);
        if (lane == 0) { vals[c] = acc; vidx[c] = n; }
    }
    __syncthreads();

    if (wave == 0) {
        double v0 = vals[lane],       v1 = vals[lane + 64];
        double v2 = vals[lane + 128], v3 = vals[lane + 192];
        int    i0 = vidx[lane],       i1 = vidx[lane + 64];
        int    i2 = vidx[lane + 128], i3 = vidx[lane + 192];
        for (int k = 0; k < KTOP; ++k) {
            // local tournament over 4 slots (value desc, index asc), static idx
            bool a01 = (v0 > v1) || (v0 == v1 && i0 < i1);
            double va = a01 ? v0 : v1; int ia = a01 ? i0 : i1; int sa = a01 ? 0 : 1;
            bool a23 = (v2 > v3) || (v2 == v3 && i2 < i3);
            double vb = a23 ? v2 : v3; int ib = a23 ? i2 : i3; int sb = a23 ? 2 : 3;
            bool ab = (va > vb) || (va == vb && ia < ib);
            double mv = ab ? va : vb; int mi = ab ? ia : ib; int slot = ab ? sa : sb;
            int owner = lane;
            #pragma unroll
            for (int off = 32; off > 0; off >>= 1) {
                double ov = __shfl_down(mv, off, 64);
                int oi = __shfl_down(mi, off, 64);
                int oo = __shfl_down(owner, off, 64);
                int os = __shfl_down(slot, off, 64);
                bool take = (ov > mv) || (ov == mv && oi < mi);
                if (take) { mv = ov; mi = oi; owner = oo; slot = os; }
            }
            int wown = __shfl(owner, 0, 64);
            int wslot = __shfl(slot, 0, 64);
            int wmi = __shfl(mi, 0, 64);
            if (lane == 0) out[(size_t)q * KTOP + k] = (float)wmi * (1.0f / 32768.0f);
            if (lane == wown) {
                v0 = (wslot == 0) ? -1e300 : v0;
                v1 = (wslot == 1) ? -1e300 : v1;
                v2 = (wslot == 2) ? -1e300 : v2;
                v3 = (wslot == 3) ? -1e300 : v3;
            }
        }
    }
}

// ---------------------------------------------------------------------------
extern "C" void kernel_launch(void* const* d_in, const int* in_sizes, int n_in,
                              void* d_out, int out_size, void* d_ws, size_t ws_size,
                              hipStream_t stream) {
    const float* prior = (const float*)d_in[0];
    const float* clip  = (const float*)d_in[1];
    const float* g1    = (const float*)d_in[2];
    const float* b1    = (const float*)d_in[3];
    const float* g2    = (const float*)d_in[4];
    const float* b2    = (const float*)d_in[5];
    float* out = (float*)d_out;

    char* ws = (char*)d_ws;
    size_t off = 0;
    double* stats1 = (double*)(ws + off); off += (size_t)N1C * 3 * sizeof(double);
    double* stats2 = (double*)(ws + off); off += (size_t)N2C * 3 * sizeof(double);
    __hip_bfloat16* x1n = (__hip_bfloat16*)(ws + off); off += (size_t)N1C * DIMN * 2;
    __hip_bfloat16* x2n = (__hip_bfloat16*)(ws + off); off += (size_t)N2C * DIMN * 2;
    __hip_bfloat16* sim = (__hip_bfloat16*)(ws + off); off += (size_t)N2C * N1C * 2;
    int* cand = (int*)(ws + off); off += (size_t)N2C * CAP * sizeof(int);
    int* cand_cnt = (int*)(ws + off); off += (size_t)N2C * sizeof(int);

    ln_norm_stats<<<N1C, 256, 0, stream>>>(prior, g1, b1, x1n, stats1);
    ln_norm_stats<<<N2C, 256, 0, stream>>>(clip, g2, b2, x2n, stats2);

    dim3 gg(N1C / BN, N2C / BM);
    sim_gemm<<<gg, 256, 0, stream>>>(x2n, x1n, sim);

    topk_cand<<<N2C, 256, 0, stream>>>(sim, cand, cand_cnt);

    rescore_topk<<<N2C, 256, 0, stream>>>(prior, clip, g1, b1, g2, b2,
                                          stats1, stats2, cand, cand_cnt, out);
}